// Round 2
// baseline (2954.069 us; speedup 1.0000x reference)
//
#include <hip/hip_runtime.h>

#define H 128

// ---------------- degree count ----------------
__global__ void deg_kernel(const int* __restrict__ src, const int* __restrict__ dst,
                           float* __restrict__ deg_u, float* __restrict__ deg_s, int E) {
    int e = blockIdx.x * blockDim.x + threadIdx.x;
    if (e < E) {
        atomicAdd(deg_u + src[e], 1.0f);
        atomicAdd(deg_s + dst[e], 1.0f);
    }
}

// ---------------- edge scatter: agg[dst[e]] += x[src[e]] ----------------
__global__ void scatter_kernel(const float* __restrict__ x, const int* __restrict__ src_idx,
                               const int* __restrict__ dst_idx, float* agg, int E) {
    int e = blockIdx.x * 2 + (threadIdx.x >> 7);
    int c = threadIdx.x & 127;
    if (e < E) {
        int s = src_idx[e];
        int d = dst_idx[e];
        atomicAdd(agg + (size_t)d * H + c, x[(size_t)s * H + c]);
    }
}

// ---------------- x_s = subreddit_x @ W + b + emb ----------------
__global__ __launch_bounds__(256) void xs_kernel(
        const float* __restrict__ X,    // [n][F]
        const float* __restrict__ W,    // [F][H]
        const float* __restrict__ b,    // [H]
        const float* __restrict__ emb,  // [n][H]
        float* __restrict__ out, int n, int F) {
    __shared__ float At[32][68];   // [k][r] transposed A tile, padded
    __shared__ float Wt[32][H];    // [k][c]

    int t = threadIdx.x;
    int row0 = blockIdx.x * 64;
    int tx = t & 31, ty = t >> 5;
    int c0 = tx * 4, r0 = ty * 8;

    float acc[8][4];
#pragma unroll
    for (int i = 0; i < 8; ++i)
#pragma unroll
        for (int j = 0; j < 4; ++j) acc[i][j] = 0.f;

    int sr = t >> 2;            // staging row 0..63
    int sk = (t & 3) * 8;       // staging k offset
    int grow = row0 + sr; if (grow > n - 1) grow = n - 1;
    const float* xrow = X + (size_t)grow * F;

    int nkb = (F + 31) / 32;
    for (int kb = 0; kb < nkb; ++kb) {
        int kbase = kb * 32;
        __syncthreads();
        // stage A^T (guarded scalar loads; K tail -> 0)
#pragma unroll
        for (int j = 0; j < 8; ++j) {
            int kk = kbase + sk + j;
            At[sk + j][sr] = (kk < F) ? xrow[kk] : 0.f;
        }
        // stage W tile (32 x 128), float4 flat copy with row guard
        const float4* wp = (const float4*)(W + (size_t)kbase * H);
        float4* wt = (float4*)&Wt[0][0];
#pragma unroll
        for (int j = 0; j < 4; ++j) {
            int f = t + j * 256;           // float4 index in [0,1024)
            int k = f >> 5;                // row within tile
            float4 v = make_float4(0.f, 0.f, 0.f, 0.f);
            if (kbase + k < F) v = wp[f];
            wt[f] = v;
        }
        __syncthreads();
#pragma unroll
        for (int k = 0; k < 32; ++k) {
            float4 w4 = *(const float4*)&Wt[k][c0];
            float4 a0 = *(const float4*)&At[k][r0];
            float4 a1 = *(const float4*)&At[k][r0 + 4];
            float a[8] = {a0.x, a0.y, a0.z, a0.w, a1.x, a1.y, a1.z, a1.w};
            float w[4] = {w4.x, w4.y, w4.z, w4.w};
#pragma unroll
            for (int i = 0; i < 8; ++i)
#pragma unroll
                for (int j = 0; j < 4; ++j) acc[i][j] += a[i] * w[j];
        }
    }

    float4 bias = *(const float4*)(b + c0);
#pragma unroll
    for (int i = 0; i < 8; ++i) {
        int gr = row0 + r0 + i;
        if (gr < n) {
            float4 em = *(const float4*)(emb + (size_t)gr * H + c0);
            float4 o;
            o.x = acc[i][0] + bias.x + em.x;
            o.y = acc[i][1] + bias.y + em.y;
            o.z = acc[i][2] + bias.z + em.z;
            o.w = acc[i][3] + bias.w + em.w;
            *(float4*)(out + (size_t)gr * H + c0) = o;
        }
    }
}

// ---------------- combine: out = act( (agg/deg) @ wl + bl + xdst @ wr ) ----------------
// NOTE: out may alias agg (in-place): each block reads its full tile before writing.
template <bool RELU>
__global__ __launch_bounds__(256) void combine_kernel(
        const float* agg, const float* __restrict__ deg,
        const float* __restrict__ xdst,
        const float* __restrict__ wl, const float* __restrict__ bl,
        const float* __restrict__ wr,
        float* out, int n) {
    __shared__ float At[32][68];
    __shared__ float Wt[32][H];
    __shared__ float rdeg_s[64];

    int t = threadIdx.x;
    int row0 = blockIdx.x * 64;
    if (t < 64) {
        int r = row0 + t;
        float d = (r < n) ? deg[r] : 1.0f;
        rdeg_s[t] = 1.0f / fmaxf(d, 1.0f);
    }
    int tx = t & 31, ty = t >> 5;
    int c0 = tx * 4, r0 = ty * 8;

    float acc[8][4];
#pragma unroll
    for (int i = 0; i < 8; ++i)
#pragma unroll
        for (int j = 0; j < 4; ++j) acc[i][j] = 0.f;

    int sr = t >> 2;
    int sk = (t & 3) * 8;
    int grow = row0 + sr; if (grow > n - 1) grow = n - 1;

    for (int kb = 0; kb < 8; ++kb) {
        const float* src = (kb < 4) ? agg : xdst;
        const float* W   = (kb < 4) ? wl : wr;
        int kbase = (kb & 3) * 32;
        __syncthreads();
        float scale = (kb < 4) ? rdeg_s[sr] : 1.0f;
        const float* p = src + (size_t)grow * H + kbase + sk;
        float4 v0 = *(const float4*)p;
        float4 v1 = *(const float4*)(p + 4);
        At[sk + 0][sr] = v0.x * scale;
        At[sk + 1][sr] = v0.y * scale;
        At[sk + 2][sr] = v0.z * scale;
        At[sk + 3][sr] = v0.w * scale;
        At[sk + 4][sr] = v1.x * scale;
        At[sk + 5][sr] = v1.y * scale;
        At[sk + 6][sr] = v1.z * scale;
        At[sk + 7][sr] = v1.w * scale;
        const float4* wp = (const float4*)(W + (size_t)kbase * H);
        float4* wt = (float4*)&Wt[0][0];
#pragma unroll
        for (int j = 0; j < 4; ++j) {
            int f = t + j * 256;
            wt[f] = wp[f];
        }
        __syncthreads();
#pragma unroll
        for (int k = 0; k < 32; ++k) {
            float4 w4 = *(const float4*)&Wt[k][c0];
            float4 a0 = *(const float4*)&At[k][r0];
            float4 a1 = *(const float4*)&At[k][r0 + 4];
            float a[8] = {a0.x, a0.y, a0.z, a0.w, a1.x, a1.y, a1.z, a1.w};
            float w[4] = {w4.x, w4.y, w4.z, w4.w};
#pragma unroll
            for (int i = 0; i < 8; ++i)
#pragma unroll
                for (int j = 0; j < 4; ++j) acc[i][j] += a[i] * w[j];
        }
    }

    float4 bias = *(const float4*)(bl + c0);
#pragma unroll
    for (int i = 0; i < 8; ++i) {
        int gr = row0 + r0 + i;
        if (gr < n) {
            float4 o;
            o.x = acc[i][0] + bias.x;
            o.y = acc[i][1] + bias.y;
            o.z = acc[i][2] + bias.z;
            o.w = acc[i][3] + bias.w;
            if (RELU) {
                o.x = fmaxf(o.x, 0.f);
                o.y = fmaxf(o.y, 0.f);
                o.z = fmaxf(o.z, 0.f);
                o.w = fmaxf(o.w, 0.f);
            }
            *(float4*)(out + (size_t)gr * H + c0) = o;
        }
    }
}

// ---------------- classifier: out[l] = dot(o_u[a], o_s[b]) ----------------
__global__ void classifier_kernel(const float* __restrict__ o_u, const float* __restrict__ o_s,
                                  const int* __restrict__ li_u, const int* __restrict__ li_s,
                                  float* __restrict__ out, int L) {
    int wave = (int)((blockIdx.x * (size_t)blockDim.x + threadIdx.x) >> 6);
    int lane = threadIdx.x & 63;
    if (wave >= L) return;
    int a = li_u[wave];
    int b = li_s[wave];
    const float* pu = o_u + (size_t)a * H;
    const float* ps = o_s + (size_t)b * H;
    float v = pu[lane] * ps[lane] + pu[lane + 64] * ps[lane + 64];
#pragma unroll
    for (int off = 32; off > 0; off >>= 1) v += __shfl_xor(v, off);
    if (lane == 0) out[wave] = v;
}

extern "C" void kernel_launch(void* const* d_in, const int* in_sizes, int n_in,
                              void* d_out, int out_size, void* d_ws, size_t ws_size,
                              hipStream_t stream) {
    const float* sub_x     = (const float*)d_in[2];
    const int*   ei        = (const int*)d_in[3];
    const int*   eli       = (const int*)d_in[4];
    const float* user_emb  = (const float*)d_in[5];
    const float* movie_emb = (const float*)d_in[6];
    const float* mlw       = (const float*)d_in[7];
    const float* mlb       = (const float*)d_in[8];
    const float* w[4][3];
    for (int i = 0; i < 4; ++i) {
        w[i][0] = (const float*)d_in[9 + 3 * i];   // wl
        w[i][1] = (const float*)d_in[10 + 3 * i];  // bl
        w[i][2] = (const float*)d_in[11 + 3 * i];  // wr
    }

    int N_u = in_sizes[5] / H;
    int N_s = in_sizes[6] / H;
    int F   = in_sizes[7] / H;
    int E   = in_sizes[3] / 2;
    int L   = in_sizes[4] / 2;

    const int* src_u = ei;
    const int* dst_s = ei + E;
    const int* lu = eli;
    const int* ls = eli + L;

    float* x_s   = (float*)d_ws;                   // [N_s][H]  (later reused as o_s)
    float* agg_s = x_s + (size_t)N_s * H;          // [N_s][H]
    float* h_s   = agg_s + (size_t)N_s * H;        // [N_s][H]
    float* agg_u = h_s + (size_t)N_s * H;          // [N_u][H]  (later o_u in-place)
    float* h_u   = agg_u + (size_t)N_u * H;        // [N_u][H]
    float* deg_u = h_u + (size_t)N_u * H;          // [N_u]
    float* deg_s = deg_u + N_u;                    // [N_s]

    size_t subBytes = (size_t)N_s * H * sizeof(float);
    size_t usrBytes = (size_t)N_u * H * sizeof(float);

    hipMemsetAsync(agg_s, 0, subBytes, stream);
    hipMemsetAsync(agg_u, 0, usrBytes, stream);
    hipMemsetAsync(deg_u, 0, (size_t)N_u * sizeof(float), stream);
    hipMemsetAsync(deg_s, 0, (size_t)N_s * sizeof(float), stream);

    deg_kernel<<<(E + 255) / 256, 256, 0, stream>>>(src_u, dst_s, deg_u, deg_s, E);
    xs_kernel<<<(N_s + 63) / 64, 256, 0, stream>>>(sub_x, mlw, mlb, movie_emb, x_s, N_s, F);

    // layer 1
    scatter_kernel<<<(E + 1) / 2, 256, 0, stream>>>(user_emb, src_u, dst_s, agg_s, E);
    combine_kernel<true><<<(N_s + 63) / 64, 256, 0, stream>>>(
        agg_s, deg_s, x_s, w[0][0], w[0][1], w[0][2], h_s, N_s);
    scatter_kernel<<<(E + 1) / 2, 256, 0, stream>>>(x_s, dst_s, src_u, agg_u, E);
    combine_kernel<true><<<(N_u + 63) / 64, 256, 0, stream>>>(
        agg_u, deg_u, user_emb, w[1][0], w[1][1], w[1][2], h_u, N_u);

    // layer 2
    hipMemsetAsync(agg_s, 0, subBytes, stream);
    hipMemsetAsync(agg_u, 0, usrBytes, stream);
    scatter_kernel<<<(E + 1) / 2, 256, 0, stream>>>(h_u, src_u, dst_s, agg_s, E);
    combine_kernel<false><<<(N_s + 63) / 64, 256, 0, stream>>>(
        agg_s, deg_s, h_s, w[2][0], w[2][1], w[2][2], x_s /*o_s*/, N_s);
    scatter_kernel<<<(E + 1) / 2, 256, 0, stream>>>(h_s, dst_s, src_u, agg_u, E);
    combine_kernel<false><<<(N_u + 63) / 64, 256, 0, stream>>>(
        agg_u, deg_u, h_u, w[3][0], w[3][1], w[3][2], agg_u /*o_u in-place*/, N_u);

    // classifier
    classifier_kernel<<<(L + 3) / 4, 256, 0, stream>>>(
        agg_u, x_s, lu, ls, (float*)d_out, L);
}

// Round 3
// 2540.013 us; speedup vs baseline: 1.1630x; 1.1630x over previous
//
#include <hip/hip_runtime.h>

#define H 128

// ---------------- degree count ----------------
__global__ void deg_kernel(const int* __restrict__ src, const int* __restrict__ dst,
                           float* __restrict__ deg_u, float* __restrict__ deg_s, int E) {
    int e = blockIdx.x * blockDim.x + threadIdx.x;
    if (e < E) {
        atomicAdd(deg_u + src[e], 1.0f);
        atomicAdd(deg_s + dst[e], 1.0f);
    }
}

// ---------------- edge scatter: agg[dst[e]] += x[src[e]] ----------------
__global__ void scatter_kernel(const float* __restrict__ x, const int* __restrict__ src_idx,
                               const int* __restrict__ dst_idx, float* agg, int E) {
    int e = blockIdx.x * 2 + (threadIdx.x >> 7);
    int c = threadIdx.x & 127;
    if (e < E) {
        int s = src_idx[e];
        int d = dst_idx[e];
        atomicAdd(agg + (size_t)d * H + c, x[(size_t)s * H + c]);
    }
}

// ---------------- x_s = subreddit_x @ W + b + emb ----------------
__global__ __launch_bounds__(256) void xs_kernel(
        const float* __restrict__ X,    // [n][F]
        const float* __restrict__ W,    // [F][H]
        const float* __restrict__ b,    // [H]
        const float* __restrict__ emb,  // [n][H]
        float* __restrict__ out, int n, int F) {
    __shared__ float At[32][68];   // [k][r] transposed A tile, padded
    __shared__ float Wt[32][H];    // [k][c]

    int t = threadIdx.x;
    int row0 = blockIdx.x * 64;
    int tx = t & 31, ty = t >> 5;
    int c0 = tx * 4, r0 = ty * 8;

    float acc[8][4];
#pragma unroll
    for (int i = 0; i < 8; ++i)
#pragma unroll
        for (int j = 0; j < 4; ++j) acc[i][j] = 0.f;

    int sr = t >> 2;            // staging row 0..63
    int sk = (t & 3) * 8;       // staging k offset
    int grow = row0 + sr; if (grow > n - 1) grow = n - 1;
    const float* xrow = X + (size_t)grow * F;

    int nkb = (F + 31) / 32;
    for (int kb = 0; kb < nkb; ++kb) {
        int kbase = kb * 32;
        __syncthreads();
#pragma unroll
        for (int j = 0; j < 8; ++j) {
            int kk = kbase + sk + j;
            At[sk + j][sr] = (kk < F) ? xrow[kk] : 0.f;
        }
        const float4* wp = (const float4*)(W + (size_t)kbase * H);
        float4* wt = (float4*)&Wt[0][0];
#pragma unroll
        for (int j = 0; j < 4; ++j) {
            int f = t + j * 256;           // float4 index in [0,1024)
            int k = f >> 5;                // row within tile
            float4 v = make_float4(0.f, 0.f, 0.f, 0.f);
            if (kbase + k < F) v = wp[f];
            wt[f] = v;
        }
        __syncthreads();
#pragma unroll
        for (int k = 0; k < 32; ++k) {
            float4 w4 = *(const float4*)&Wt[k][c0];
            float4 a0 = *(const float4*)&At[k][r0];
            float4 a1 = *(const float4*)&At[k][r0 + 4];
            float a[8] = {a0.x, a0.y, a0.z, a0.w, a1.x, a1.y, a1.z, a1.w};
            float w[4] = {w4.x, w4.y, w4.z, w4.w};
#pragma unroll
            for (int i = 0; i < 8; ++i)
#pragma unroll
                for (int j = 0; j < 4; ++j) acc[i][j] += a[i] * w[j];
        }
    }

    float4 bias = *(const float4*)(b + c0);
#pragma unroll
    for (int i = 0; i < 8; ++i) {
        int gr = row0 + r0 + i;
        if (gr < n) {
            float4 em = *(const float4*)(emb + (size_t)gr * H + c0);
            float4 o;
            o.x = acc[i][0] + bias.x + em.x;
            o.y = acc[i][1] + bias.y + em.y;
            o.z = acc[i][2] + bias.z + em.z;
            o.w = acc[i][3] + bias.w + em.w;
            *(float4*)(out + (size_t)gr * H + c0) = o;
        }
    }
}

// ---------------- combine (2-GEMM, s-side): out = act((agg/deg)@wl + bl + xdst@wr) ----------------
template <bool RELU>
__global__ __launch_bounds__(256) void combine_kernel(
        const float* __restrict__ agg, const float* __restrict__ deg,
        const float* __restrict__ xdst,
        const float* __restrict__ wl, const float* __restrict__ bl,
        const float* __restrict__ wr,
        float* __restrict__ out, int n) {
    __shared__ float At[32][68];
    __shared__ float Wt[32][H];
    __shared__ float rdeg_s[64];

    int t = threadIdx.x;
    int row0 = blockIdx.x * 64;
    if (t < 64) {
        int r = row0 + t;
        float d = (r < n) ? deg[r] : 1.0f;
        rdeg_s[t] = 1.0f / fmaxf(d, 1.0f);
    }
    int tx = t & 31, ty = t >> 5;
    int c0 = tx * 4, r0 = ty * 8;

    float acc[8][4];
#pragma unroll
    for (int i = 0; i < 8; ++i)
#pragma unroll
        for (int j = 0; j < 4; ++j) acc[i][j] = 0.f;

    int sr = t >> 2;
    int sk = (t & 3) * 8;
    int grow = row0 + sr; if (grow > n - 1) grow = n - 1;

    for (int kb = 0; kb < 8; ++kb) {
        const float* src = (kb < 4) ? agg : xdst;
        const float* W   = (kb < 4) ? wl : wr;
        int kbase = (kb & 3) * 32;
        __syncthreads();
        float scale = (kb < 4) ? rdeg_s[sr] : 1.0f;
        const float* p = src + (size_t)grow * H + kbase + sk;
        float4 v0 = *(const float4*)p;
        float4 v1 = *(const float4*)(p + 4);
        At[sk + 0][sr] = v0.x * scale;
        At[sk + 1][sr] = v0.y * scale;
        At[sk + 2][sr] = v0.z * scale;
        At[sk + 3][sr] = v0.w * scale;
        At[sk + 4][sr] = v1.x * scale;
        At[sk + 5][sr] = v1.y * scale;
        At[sk + 6][sr] = v1.z * scale;
        At[sk + 7][sr] = v1.w * scale;
        const float4* wp = (const float4*)(W + (size_t)kbase * H);
        float4* wt = (float4*)&Wt[0][0];
#pragma unroll
        for (int j = 0; j < 4; ++j) {
            int f = t + j * 256;
            wt[f] = wp[f];
        }
        __syncthreads();
#pragma unroll
        for (int k = 0; k < 32; ++k) {
            float4 w4 = *(const float4*)&Wt[k][c0];
            float4 a0 = *(const float4*)&At[k][r0];
            float4 a1 = *(const float4*)&At[k][r0 + 4];
            float a[8] = {a0.x, a0.y, a0.z, a0.w, a1.x, a1.y, a1.z, a1.w};
            float w[4] = {w4.x, w4.y, w4.z, w4.w};
#pragma unroll
            for (int i = 0; i < 8; ++i)
#pragma unroll
                for (int j = 0; j < 4; ++j) acc[i][j] += a[i] * w[j];
        }
    }

    float4 bias = *(const float4*)(bl + c0);
#pragma unroll
    for (int i = 0; i < 8; ++i) {
        int gr = row0 + r0 + i;
        if (gr < n) {
            float4 o;
            o.x = acc[i][0] + bias.x;
            o.y = acc[i][1] + bias.y;
            o.z = acc[i][2] + bias.z;
            o.w = acc[i][3] + bias.w;
            if (RELU) {
                o.x = fmaxf(o.x, 0.f);
                o.y = fmaxf(o.y, 0.f);
                o.z = fmaxf(o.z, 0.f);
                o.w = fmaxf(o.w, 0.f);
            }
            *(float4*)(out + (size_t)gr * H + c0) = o;
        }
    }
}

// ---------------- plain GEMM: out[n][128] = A[n][128] @ W[128][128] ----------------
__global__ __launch_bounds__(256) void gemm_k(
        const float* __restrict__ A, const float* __restrict__ W,
        float* __restrict__ out, int n) {
    __shared__ float At[32][68];
    __shared__ float Wt[32][H];

    int t = threadIdx.x;
    int row0 = blockIdx.x * 64;
    int tx = t & 31, ty = t >> 5;
    int c0 = tx * 4, r0 = ty * 8;

    float acc[8][4];
#pragma unroll
    for (int i = 0; i < 8; ++i)
#pragma unroll
        for (int j = 0; j < 4; ++j) acc[i][j] = 0.f;

    int sr = t >> 2;
    int sk = (t & 3) * 8;
    int grow = row0 + sr; if (grow > n - 1) grow = n - 1;

    for (int kb = 0; kb < 4; ++kb) {
        int kbase = kb * 32;
        __syncthreads();
        const float* p = A + (size_t)grow * H + kbase + sk;
        float4 v0 = *(const float4*)p;
        float4 v1 = *(const float4*)(p + 4);
        At[sk + 0][sr] = v0.x;
        At[sk + 1][sr] = v0.y;
        At[sk + 2][sr] = v0.z;
        At[sk + 3][sr] = v0.w;
        At[sk + 4][sr] = v1.x;
        At[sk + 5][sr] = v1.y;
        At[sk + 6][sr] = v1.z;
        At[sk + 7][sr] = v1.w;
        const float4* wp = (const float4*)(W + (size_t)kbase * H);
        float4* wt = (float4*)&Wt[0][0];
#pragma unroll
        for (int j = 0; j < 4; ++j) {
            int f = t + j * 256;
            wt[f] = wp[f];
        }
        __syncthreads();
#pragma unroll
        for (int k = 0; k < 32; ++k) {
            float4 w4 = *(const float4*)&Wt[k][c0];
            float4 a0 = *(const float4*)&At[k][r0];
            float4 a1 = *(const float4*)&At[k][r0 + 4];
            float a[8] = {a0.x, a0.y, a0.z, a0.w, a1.x, a1.y, a1.z, a1.w};
            float w[4] = {w4.x, w4.y, w4.z, w4.w};
#pragma unroll
            for (int i = 0; i < 8; ++i)
#pragma unroll
                for (int j = 0; j < 4; ++j) acc[i][j] += a[i] * w[j];
        }
    }

#pragma unroll
    for (int i = 0; i < 8; ++i) {
        int gr = row0 + r0 + i;
        if (gr < n) {
            float4 o = make_float4(acc[i][0], acc[i][1], acc[i][2], acc[i][3]);
            *(float4*)(out + (size_t)gr * H + c0) = o;
        }
    }
}

// ---------------- user combine (1-GEMM): out = act(agg*rdeg + b + X@W) ----------------
template <bool RELU>
__global__ __launch_bounds__(256) void ucombine_kernel(
        const float* __restrict__ agg, const float* __restrict__ deg,
        const float* __restrict__ X,
        const float* __restrict__ W, const float* __restrict__ b,
        float* __restrict__ out, int n) {
    __shared__ float At[32][68];
    __shared__ float Wt[32][H];
    __shared__ float rdeg_s[64];

    int t = threadIdx.x;
    int row0 = blockIdx.x * 64;
    if (t < 64) {
        int r = row0 + t;
        float d = (r < n) ? deg[r] : 1.0f;
        rdeg_s[t] = 1.0f / fmaxf(d, 1.0f);
    }
    int tx = t & 31, ty = t >> 5;
    int c0 = tx * 4, r0 = ty * 8;

    float acc[8][4];
#pragma unroll
    for (int i = 0; i < 8; ++i)
#pragma unroll
        for (int j = 0; j < 4; ++j) acc[i][j] = 0.f;

    int sr = t >> 2;
    int sk = (t & 3) * 8;
    int grow = row0 + sr; if (grow > n - 1) grow = n - 1;

    for (int kb = 0; kb < 4; ++kb) {
        int kbase = kb * 32;
        __syncthreads();
        const float* p = X + (size_t)grow * H + kbase + sk;
        float4 v0 = *(const float4*)p;
        float4 v1 = *(const float4*)(p + 4);
        At[sk + 0][sr] = v0.x;
        At[sk + 1][sr] = v0.y;
        At[sk + 2][sr] = v0.z;
        At[sk + 3][sr] = v0.w;
        At[sk + 4][sr] = v1.x;
        At[sk + 5][sr] = v1.y;
        At[sk + 6][sr] = v1.z;
        At[sk + 7][sr] = v1.w;
        const float4* wp = (const float4*)(W + (size_t)kbase * H);
        float4* wt = (float4*)&Wt[0][0];
#pragma unroll
        for (int j = 0; j < 4; ++j) {
            int f = t + j * 256;
            wt[f] = wp[f];
        }
        __syncthreads();
#pragma unroll
        for (int k = 0; k < 32; ++k) {
            float4 w4 = *(const float4*)&Wt[k][c0];
            float4 a0 = *(const float4*)&At[k][r0];
            float4 a1 = *(const float4*)&At[k][r0 + 4];
            float a[8] = {a0.x, a0.y, a0.z, a0.w, a1.x, a1.y, a1.z, a1.w};
            float w[4] = {w4.x, w4.y, w4.z, w4.w};
#pragma unroll
            for (int i = 0; i < 8; ++i)
#pragma unroll
                for (int j = 0; j < 4; ++j) acc[i][j] += a[i] * w[j];
        }
    }

    float4 bias = *(const float4*)(b + c0);
#pragma unroll
    for (int i = 0; i < 8; ++i) {
        int gr = row0 + r0 + i;
        if (gr < n) {
            float rd = rdeg_s[r0 + i];
            float4 ag = *(const float4*)(agg + (size_t)gr * H + c0);
            float4 o;
            o.x = acc[i][0] + bias.x + ag.x * rd;
            o.y = acc[i][1] + bias.y + ag.y * rd;
            o.z = acc[i][2] + bias.z + ag.z * rd;
            o.w = acc[i][3] + bias.w + ag.w * rd;
            if (RELU) {
                o.x = fmaxf(o.x, 0.f);
                o.y = fmaxf(o.y, 0.f);
                o.z = fmaxf(o.z, 0.f);
                o.w = fmaxf(o.w, 0.f);
            }
            *(float4*)(out + (size_t)gr * H + c0) = o;
        }
    }
}

// ---------------- 128x128 transpose ----------------
__global__ void transpose128(const float* __restrict__ in, float* __restrict__ outT) {
    for (int idx = threadIdx.x; idx < H * H; idx += blockDim.x) {
        int i = idx >> 7, j = idx & 127;
        outT[(size_t)j * H + i] = in[idx];
    }
}

// ---------------- classifier (fused l2_s2u user side) ----------------
// out[l] = (agg2[a]*rdeg_u[a] + bl2) . o_s[b] + h_u[a] . t_s[b]
__global__ void classifier2_kernel(
        const float* __restrict__ agg2, const float* __restrict__ deg_u,
        const float* __restrict__ bl2,
        const float* __restrict__ h_u,
        const float* __restrict__ o_s, const float* __restrict__ t_s,
        const int* __restrict__ li_u, const int* __restrict__ li_s,
        float* __restrict__ out, int L) {
    int e = blockIdx.x * 4 + (threadIdx.x >> 6);
    int lane = threadIdx.x & 63;
    if (e >= L) return;
    int a = li_u[e];
    int b = li_s[e];
    float rd = 1.0f / fmaxf(deg_u[a], 1.0f);
    float2 ag = ((const float2*)(agg2 + (size_t)a * H))[lane];
    float2 bb = ((const float2*)bl2)[lane];
    float2 os = ((const float2*)(o_s + (size_t)b * H))[lane];
    float2 hu = ((const float2*)(h_u + (size_t)a * H))[lane];
    float2 ts = ((const float2*)(t_s + (size_t)b * H))[lane];
    float v = (ag.x * rd + bb.x) * os.x + (ag.y * rd + bb.y) * os.y
            + hu.x * ts.x + hu.y * ts.y;
#pragma unroll
    for (int off = 32; off > 0; off >>= 1) v += __shfl_xor(v, off);
    if (lane == 0) out[e] = v;
}

extern "C" void kernel_launch(void* const* d_in, const int* in_sizes, int n_in,
                              void* d_out, int out_size, void* d_ws, size_t ws_size,
                              hipStream_t stream) {
    const float* sub_x     = (const float*)d_in[2];
    const int*   ei        = (const int*)d_in[3];
    const int*   eli       = (const int*)d_in[4];
    const float* user_emb  = (const float*)d_in[5];
    const float* movie_emb = (const float*)d_in[6];
    const float* mlw       = (const float*)d_in[7];
    const float* mlb       = (const float*)d_in[8];
    const float* w[4][3];
    for (int i = 0; i < 4; ++i) {
        w[i][0] = (const float*)d_in[9 + 3 * i];   // wl
        w[i][1] = (const float*)d_in[10 + 3 * i];  // bl
        w[i][2] = (const float*)d_in[11 + 3 * i];  // wr
    }
    // order: 0=l1_u2s, 1=l1_s2u, 2=l2_u2s, 3=l2_s2u

    int N_u = in_sizes[5] / H;
    int N_s = in_sizes[6] / H;
    int E   = in_sizes[3] / 2;
    int L   = in_sizes[4] / 2;

    const int* src_u = ei;
    const int* dst_s = ei + E;
    const int* lu = eli;
    const int* ls = eli + L;

    float* x_s   = (float*)d_ws;                   // [N_s][H]  (later o_s)
    float* agg_s = x_s + (size_t)N_s * H;          // [N_s][H]
    float* h_s   = agg_s + (size_t)N_s * H;        // [N_s][H]
    float* ybuf  = h_s + (size_t)N_s * H;          // [N_s][H]
    float* t_s   = ybuf + (size_t)N_s * H;         // [N_s][H]
    float* agg_u = t_s + (size_t)N_s * H;          // [N_u][H]
    float* h_u   = agg_u + (size_t)N_u * H;        // [N_u][H]
    float* deg_u = h_u + (size_t)N_u * H;          // [N_u]
    float* deg_s = deg_u + N_u;                    // [N_s]
    float* wrT   = deg_s + N_s;                    // [H][H]

    size_t subBytes = (size_t)N_s * H * sizeof(float);
    size_t usrBytes = (size_t)N_u * H * sizeof(float);

    hipMemsetAsync(agg_s, 0, subBytes, stream);
    hipMemsetAsync(agg_u, 0, usrBytes, stream);
    hipMemsetAsync(deg_u, 0, (size_t)N_u * sizeof(float), stream);
    hipMemsetAsync(deg_s, 0, (size_t)N_s * sizeof(float), stream);

    deg_kernel<<<(E + 255) / 256, 256, 0, stream>>>(src_u, dst_s, deg_u, deg_s, E);
    xs_kernel<<<(N_s + 63) / 64, 256, 0, stream>>>(sub_x, mlw, mlb, movie_emb, x_s, N_s, 1250);

    int gs = (N_s + 63) / 64;
    int gu = (N_u + 63) / 64;

    // ---- layer 1 ----
    // s2u transform-first: y = x_s @ l1_s2u_wl, scatter into agg_u
    gemm_k<<<gs, 256, 0, stream>>>(x_s, w[1][0], ybuf, N_s);
    scatter_kernel<<<(E + 1) / 2, 256, 0, stream>>>(ybuf, dst_s, src_u, agg_u, E);
    // u2s scatter: user_emb into agg_s
    scatter_kernel<<<(E + 1) / 2, 256, 0, stream>>>(user_emb, src_u, dst_s, agg_s, E);
    // h_s = relu((agg_s/deg)@wl + bl + x_s@wr)
    combine_kernel<true><<<gs, 256, 0, stream>>>(
        agg_s, deg_s, x_s, w[0][0], w[0][1], w[0][2], h_s, N_s);
    // h_u = relu(agg_u*rdeg + bl + user_emb@wr)
    ucombine_kernel<true><<<gu, 256, 0, stream>>>(
        agg_u, deg_u, user_emb, w[1][2], w[1][1], h_u, N_u);

    // ---- layer 2 ----
    hipMemsetAsync(agg_s, 0, subBytes, stream);
    hipMemsetAsync(agg_u, 0, usrBytes, stream);
    // u2s: scatter h_u into agg_s, combine -> o_s (into x_s buffer)
    scatter_kernel<<<(E + 1) / 2, 256, 0, stream>>>(h_u, src_u, dst_s, agg_s, E);
    combine_kernel<false><<<gs, 256, 0, stream>>>(
        agg_s, deg_s, h_s, w[2][0], w[2][1], w[2][2], x_s /*o_s*/, N_s);
    // s2u transform-first: y2 = h_s @ l2_s2u_wl, scatter into agg_u
    gemm_k<<<gs, 256, 0, stream>>>(h_s, w[3][0], ybuf, N_s);
    scatter_kernel<<<(E + 1) / 2, 256, 0, stream>>>(ybuf, dst_s, src_u, agg_u, E);
    // t_s = o_s @ wr^T
    transpose128<<<1, 256, 0, stream>>>(w[3][2], wrT);
    gemm_k<<<gs, 256, 0, stream>>>(x_s /*o_s*/, wrT, t_s, N_s);

    // ---- classifier ----
    classifier2_kernel<<<(L + 3) / 4, 256, 0, stream>>>(
        agg_u, deg_u, w[3][1], h_u, x_s /*o_s*/, t_s, lu, ls, (float*)d_out, L);
}